// Round 1
// baseline (1110.216 us; speedup 1.0000x reference)
//
#include <hip/hip_runtime.h>
#include <math.h>

#define HW   2816           // 32*88
#define IMGS 6
#define DD   59
#define NV   16384          // 128*128 BEV cells (B=1)
#define COUT 128

// ---------------- small prep kernels ----------------

__global__ void zero_kernel(int* __restrict__ p, int n){
    int i = blockIdx.x*256 + threadIdx.x;
    if (i < n) p[i] = 0;
}

__global__ void bn_prep(const float* __restrict__ c1b, const float* __restrict__ g1,
                        const float* __restrict__ bb1, const float* __restrict__ m1,
                        const float* __restrict__ v1,
                        const float* __restrict__ c2b, const float* __restrict__ g2,
                        const float* __restrict__ bb2, const float* __restrict__ m2,
                        const float* __restrict__ v2,
                        float* __restrict__ s1, float* __restrict__ t1,
                        float* __restrict__ s2, float* __restrict__ t2){
    int c = threadIdx.x;   // 256
    float i1 = g1[c]/sqrtf(v1[c]+1e-3f);
    s1[c] = i1; t1[c] = (c1b[c]-m1[c])*i1 + bb1[c];
    float i2 = g2[c]/sqrtf(v2[c]+1e-3f);
    s2[c] = i2; t2[c] = (c2b[c]-m2[c])*i2 + bb2[c];
}

// OIHW -> [tap][ci][co]
__global__ void wtrans(const float* __restrict__ w, float* __restrict__ wT,
                       int CO, int CI, int KK){
    int idx = blockIdx.x*256 + threadIdx.x;
    if (idx >= CO*CI*KK) return;
    int co  = idx/(CI*KK);
    int r   = idx - co*CI*KK;
    int ci  = r/KK;
    int tap = r - ci*KK;
    wT[(tap*CI + ci)*CO + co] = w[idx];
}

// ---------------- depth distribution + voxel histogram ----------------

__global__ void depth_count(const float* __restrict__ rel, const int* __restrict__ vids,
                            const float* __restrict__ lsc, const float* __restrict__ shf,
                            const float* __restrict__ lsg,
                            float* __restrict__ dd, int* __restrict__ counts){
    int g = blockIdx.x*256 + threadIdx.x;     // 16896 threads exactly
    if (g >= IMGS*HW) return;
    int bn = g/HW, p = g - bn*HW;
    float scale = expf(lsc[0]);
    float sh    = shf[0];
    float sig   = fminf(fmaxf(expf(lsg[0]), 0.1f), 20.f);
    float inv   = 1.f/sig;
    float metric = fminf(fmaxf(scale*rel[g] + sh, 0.5f), 150.f);
    // max logit = -(distance to nearest bin)/sigma ; bins = 1..59
    float nb = fminf(fmaxf(rintf(metric), 1.f), 59.f);
    float mx = -fabsf(metric - nb)*inv;
    float sum = 0.f;
    for (int d = 0; d < DD; ++d)
        sum += expf(-fabsf(metric - (float)(d+1))*inv - mx);
    float rs = 1.f/sum;
    for (int d = 0; d < DD; ++d){
        int idx = (bn*DD + d)*HW + p;
        dd[idx] = expf(-fabsf(metric - (float)(d+1))*inv - mx)*rs;
        atomicAdd(&counts[vids[idx]], 1);
    }
}

// exclusive prefix sum over NV=16384 counters, one block of 256 threads
__global__ void scan_kernel(const int* __restrict__ counts, int* __restrict__ offsets){
    __shared__ int part[256];
    int t = threadIdx.x;
    int base = t*64;
    int s = 0;
    for (int i = 0; i < 64; ++i) s += counts[base+i];
    part[t] = s;
    __syncthreads();
    for (int off = 1; off < 256; off <<= 1){
        int v = (t >= off) ? part[t-off] : 0;
        __syncthreads();
        part[t] += v;
        __syncthreads();
    }
    int run = (t == 0) ? 0 : part[t-1];
    for (int i = 0; i < 64; ++i){
        offsets[base+i] = run;
        run += counts[base+i];
    }
}

__global__ void fill_kernel(const float* __restrict__ dd, const int* __restrict__ vids,
                            const int* __restrict__ offsets, int* __restrict__ cursor,
                            int2* __restrict__ records){
    int g = blockIdx.x*256 + threadIdx.x;
    if (g >= IMGS*HW) return;
    int bn = g/HW, p = g - bn*HW;
    for (int d = 0; d < DD; ++d){
        int idx = (bn*DD + d)*HW + p;
        int v   = vids[idx];
        float w = dd[idx];
        int pos = atomicAdd(&cursor[v], 1);
        records[offsets[v] + pos] = make_int2(g, __float_as_int(w));
    }
}

// ---------------- direct conv (implicit GEMM over taps), fp32 ----------------
// tile: 64 pixels x 128 out-channels, 256 threads, per-thread 4x8
template<int KH, int KW, bool BN_RELU, bool TOUT>
__global__ __launch_bounds__(256,2) void conv_kernel(
    const float* __restrict__ in,     // [IMGS][CI][HW]
    const float* __restrict__ wT,     // [KH*KW][CI][CO]
    const float* __restrict__ scale,  // [CO] (BN) or unused
    const float* __restrict__ bias,   // [CO]
    float* __restrict__ out,          // !TOUT: [IMGS][CO][HW]   TOUT: [IMGS*HW][CO]
    int CI, int CO)
{
    constexpr int TM = 64, TN = 128, CIT = 16;
    __shared__ float As[CIT*TM];
    __shared__ float Bs[CIT*TN];
    const int img = blockIdx.z;
    const int m0  = blockIdx.x*TM;
    const int n0  = blockIdx.y*TN;
    const int t   = threadIdx.x;
    const int tm  = (t & 15)*4;
    const int tn  = (t >> 4)*8;
    const float* inI = in + (size_t)img*CI*HW;

    int ay[4], ax[4];
#pragma unroll
    for (int r = 0; r < 4; ++r){
        int m = (t + r*256) & 63;
        int p = m0 + m;
        ay[r] = p/88; ax[r] = p - ay[r]*88;
    }

    float acc[4][8];
#pragma unroll
    for (int i = 0; i < 4; ++i)
#pragma unroll
        for (int j = 0; j < 8; ++j) acc[i][j] = 0.f;

    for (int tap = 0; tap < KH*KW; ++tap){
        const int dy = tap/KW - KH/2;
        const int dx = tap%KW - KW/2;
        for (int ci0 = 0; ci0 < CI; ci0 += CIT){
            // stage A: 16 ci x 64 px  (4 elems/thread)
#pragma unroll
            for (int r = 0; r < 4; ++r){
                int e = t + r*256;
                int i = e >> 6;
                int yy = ay[r] + dy, xx = ax[r] + dx;
                float v = 0.f;
                if ((unsigned)yy < 32u && (unsigned)xx < 88u)
                    v = inI[(size_t)(ci0+i)*HW + yy*88 + xx];
                As[e] = v;
            }
            // stage B: 16 ci x 128 co (8 elems/thread)
            const float* wp = wT + (size_t)(tap*CI + ci0)*CO + n0;
#pragma unroll
            for (int r = 0; r < 8; ++r){
                int e = t + r*256;
                int i = e >> 7, n = e & 127;
                Bs[e] = wp[(size_t)i*CO + n];
            }
            __syncthreads();
#pragma unroll
            for (int i = 0; i < CIT; ++i){
                float4 a  = *(const float4*)&As[i*TM + tm];
                float4 b0 = *(const float4*)&Bs[i*TN + tn];
                float4 b1 = *(const float4*)&Bs[i*TN + tn + 4];
                float av[4] = {a.x, a.y, a.z, a.w};
                float bv[8] = {b0.x, b0.y, b0.z, b0.w, b1.x, b1.y, b1.z, b1.w};
#pragma unroll
                for (int pi = 0; pi < 4; ++pi)
#pragma unroll
                    for (int ni = 0; ni < 8; ++ni)
                        acc[pi][ni] = fmaf(av[pi], bv[ni], acc[pi][ni]);
            }
            __syncthreads();
        }
    }
    // epilogue: BN(scale,bias)+ReLU  or  +bias
#pragma unroll
    for (int ni = 0; ni < 8; ++ni){
        int co = n0 + tn + ni;
        if (BN_RELU){
            float sc = scale[co], bi = bias[co];
#pragma unroll
            for (int pi = 0; pi < 4; ++pi)
                acc[pi][ni] = fmaxf(fmaf(acc[pi][ni], sc, bi), 0.f);
        } else {
            float bi = bias[co];
#pragma unroll
            for (int pi = 0; pi < 4; ++pi)
                acc[pi][ni] += bi;
        }
    }
    if (TOUT){
#pragma unroll
        for (int pi = 0; pi < 4; ++pi){
            float* o = out + (size_t)(img*HW + m0 + tm + pi)*CO + n0 + tn;
            *(float4*)o       = make_float4(acc[pi][0], acc[pi][1], acc[pi][2], acc[pi][3]);
            *(float4*)(o + 4) = make_float4(acc[pi][4], acc[pi][5], acc[pi][6], acc[pi][7]);
        }
    } else {
#pragma unroll
        for (int ni = 0; ni < 8; ++ni){
            int co = n0 + tn + ni;
            float* o = out + ((size_t)img*CO + co)*HW + m0 + tm;
            *(float4*)o = make_float4(acc[0][ni], acc[1][ni], acc[2][ni], acc[3][ni]);
        }
    }
}

// ---------------- atomic-free splat: gather per voxel ----------------

__global__ __launch_bounds__(128) void gather_kernel(
    const int2* __restrict__ records, const int* __restrict__ offsets,
    const int* __restrict__ counts, const float* __restrict__ feat,
    float* __restrict__ bev_t){
    int v = blockIdx.x;
    int c = threadIdx.x;
    int off = offsets[v], n = counts[v];
    float acc = 0.f;
    for (int i = 0; i < n; ++i){
        int2 r = records[off + i];
        acc = fmaf(__int_as_float(r.y), feat[(size_t)r.x*COUT + c], acc);
    }
    bev_t[(size_t)v*COUT + c] = acc;
}

// bev_t[v][c] -> out[c][v]
__global__ void transpose_out(const float* __restrict__ bev_t, float* __restrict__ out){
    __shared__ float tile[32][33];
    int v0 = blockIdx.x*32, c0 = blockIdx.y*32;
    int tx = threadIdx.x & 31, ty = threadIdx.x >> 5;   // 256 threads: ty 0..7
#pragma unroll
    for (int k = 0; k < 4; ++k)
        tile[ty + 8*k][tx] = bev_t[(size_t)(v0 + ty + 8*k)*COUT + c0 + tx];
    __syncthreads();
#pragma unroll
    for (int k = 0; k < 4; ++k)
        out[(size_t)(c0 + ty + 8*k)*NV + v0 + tx] = tile[tx][ty + 8*k];
}

// ---------------- launch ----------------

extern "C" void kernel_launch(void* const* d_in, const int* in_sizes, int n_in,
                              void* d_out, int out_size, void* d_ws, size_t ws_size,
                              hipStream_t stream){
    const float* rel  = (const float*)d_in[0];
    const float* imgf = (const float*)d_in[1];
    const int*   vids = (const int*)d_in[2];
    const float* lsc  = (const float*)d_in[3];
    const float* shf  = (const float*)d_in[4];
    const float* lsg  = (const float*)d_in[5];
    const float* w1   = (const float*)d_in[6];
    const float* b1   = (const float*)d_in[7];
    const float* g1   = (const float*)d_in[8];
    const float* bb1  = (const float*)d_in[9];
    const float* m1   = (const float*)d_in[10];
    const float* v1   = (const float*)d_in[11];
    const float* w2   = (const float*)d_in[12];
    const float* b2   = (const float*)d_in[13];
    const float* g2   = (const float*)d_in[14];
    const float* bb2  = (const float*)d_in[15];
    const float* m2   = (const float*)d_in[16];
    const float* v2   = (const float*)d_in[17];
    const float* w3   = (const float*)d_in[18];
    const float* b3   = (const float*)d_in[19];

    char* ws = (char*)d_ws;
    size_t o = 0;
    auto alloc = [&](size_t bytes)->char*{
        char* p = ws + o;
        o += (bytes + 255) & ~(size_t)255;
        return p;
    };
    int*   counts  = (int*)alloc((size_t)2*NV*4);   // counts | cursor (contiguous)
    int*   cursor  = counts + NV;
    int*   offsets = (int*)alloc((size_t)NV*4);
    float* wT1 = (float*)alloc((size_t)589824*4);
    float* wT2 = (float*)alloc((size_t)589824*4);
    float* wT3 = (float*)alloc((size_t)32768*4);
    float* s1  = (float*)alloc(256*4);
    float* t1  = (float*)alloc(256*4);
    float* s2  = (float*)alloc(256*4);
    float* t2  = (float*)alloc(256*4);
    float* h1  = (float*)alloc((size_t)IMGS*256*HW*4);      // 17.3 MB
    float* h2  = (float*)alloc((size_t)IMGS*256*HW*4);      // 17.3 MB
    float* feat_t = (float*)alloc((size_t)IMGS*HW*COUT*4);  // 8.65 MB
    float* bev_t  = (float*)alloc((size_t)NV*COUT*4);       // 8 MB
    // h1/h2 are dead after conv3 -> alias the splat scratch into them
    float* dd      = h1;        // 4 MB  <= 17.3 MB
    int2*  records = (int2*)h2; // 8 MB  <= 17.3 MB

    // feature net
    bn_prep<<<1,256,0,stream>>>(b1,g1,bb1,m1,v1, b2,g2,bb2,m2,v2, s1,t1,s2,t2);
    wtrans<<<2304,256,0,stream>>>(w1, wT1, 256, 256, 9);
    wtrans<<<2304,256,0,stream>>>(w2, wT2, 256, 256, 9);
    wtrans<<<128,256,0,stream>>>(w3, wT3, 128, 256, 1);
    conv_kernel<3,3,true ,false><<<dim3(44,2,6),256,0,stream>>>(imgf, wT1, s1, t1, h1, 256, 256);
    conv_kernel<3,3,true ,false><<<dim3(44,2,6),256,0,stream>>>(h1,   wT2, s2, t2, h2, 256, 256);
    conv_kernel<1,1,false,true ><<<dim3(44,1,6),256,0,stream>>>(h2,   wT3, s1, b3, feat_t, 256, 128);

    // depth dist + binning (after convs: dd/records alias h1/h2)
    zero_kernel<<<(2*NV + 255)/256,256,0,stream>>>(counts, 2*NV);
    depth_count<<<66,256,0,stream>>>(rel, vids, lsc, shf, lsg, dd, counts);
    scan_kernel<<<1,256,0,stream>>>(counts, offsets);
    fill_kernel<<<66,256,0,stream>>>(dd, vids, offsets, cursor, records);

    // splat (atomic-free gather) + output transpose
    gather_kernel<<<NV,128,0,stream>>>(records, offsets, counts, feat_t, bev_t);
    transpose_out<<<dim3(512,4),256,0,stream>>>(bev_t, (float*)d_out);
}

// Round 2
// 512.427 us; speedup vs baseline: 2.1666x; 2.1666x over previous
//
#include <hip/hip_runtime.h>
#include <math.h>

#define HW   2816           // 32*88
#define IMGS 6
#define DD   59
#define NV   16384          // 128*128 BEV cells (B=1)
#define COUT 128

typedef _Float16 half8 __attribute__((ext_vector_type(8)));
typedef float f32x4 __attribute__((ext_vector_type(4)));

__device__ __forceinline__ void glds16(const void* g, const _Float16* l){
    __builtin_amdgcn_global_load_lds(
        (const __attribute__((address_space(1))) void*)g,
        (__attribute__((address_space(3))) void*)(_Float16*)l, 16, 0, 0);
}

// ---------------- small prep kernels ----------------

__global__ void zero_kernel(int* __restrict__ p, int n){
    int i = blockIdx.x*256 + threadIdx.x;
    if (i < n) p[i] = 0;
}

__global__ void bn_prep(const float* __restrict__ c1b, const float* __restrict__ g1,
                        const float* __restrict__ bb1, const float* __restrict__ m1,
                        const float* __restrict__ v1,
                        const float* __restrict__ c2b, const float* __restrict__ g2,
                        const float* __restrict__ bb2, const float* __restrict__ m2,
                        const float* __restrict__ v2,
                        float* __restrict__ s1, float* __restrict__ t1,
                        float* __restrict__ s2, float* __restrict__ t2){
    int c = threadIdx.x;   // 256
    float i1 = g1[c]/sqrtf(v1[c]+1e-3f);
    s1[c] = i1; t1[c] = (c1b[c]-m1[c])*i1 + bb1[c];
    float i2 = g2[c]/sqrtf(v2[c]+1e-3f);
    s2[c] = i2; t2[c] = (c2b[c]-m2[c])*i2 + bb2[c];
}

// OIHW -> [tap][co][ci] fp16 hi/lo split
__global__ void wsplit(const float* __restrict__ w, _Float16* __restrict__ wh,
                       _Float16* __restrict__ wl, int CO, int CI, int KK){
    int idx = blockIdx.x*256 + threadIdx.x;
    if (idx >= CO*CI*KK) return;
    int co  = idx/(CI*KK);
    int r   = idx - co*CI*KK;
    int ci  = r/KK;
    int tap = r - ci*KK;
    float v = w[idx];
    _Float16 h = (_Float16)v;
    size_t o = ((size_t)tap*CO + co)*CI + ci;
    wh[o] = h; wl[o] = (_Float16)(v - (float)h);
}

// imgf [img][ci=256][pix=2816] fp32 -> pixel-major fp16 hi/lo [img*2816+pix][256]
__global__ void tsplit(const float* __restrict__ imgf,
                       _Float16* __restrict__ inH, _Float16* __restrict__ inL){
    __shared__ float tile[32][33];
    int img = blockIdx.z;
    int p0 = blockIdx.x*32, c0 = blockIdx.y*32;
    int tx = threadIdx.x & 31, ty = threadIdx.x >> 5;   // 32 x 8
#pragma unroll
    for (int k = 0; k < 4; ++k)
        tile[ty + 8*k][tx] = imgf[((size_t)(img*256 + c0 + ty + 8*k))*HW + p0 + tx];
    __syncthreads();
#pragma unroll
    for (int k = 0; k < 4; ++k){
        int pr = ty + 8*k, cc = tx;
        float v = tile[cc][pr];
        _Float16 h = (_Float16)v;
        size_t o = ((size_t)(img*HW + p0 + pr))*256 + c0 + cc;
        inH[o] = h; inL[o] = (_Float16)(v - (float)h);
    }
}

// ---------------- depth distribution + voxel histogram ----------------

__global__ void depth_count(const float* __restrict__ rel, const int* __restrict__ vids,
                            const float* __restrict__ lsc, const float* __restrict__ shf,
                            const float* __restrict__ lsg,
                            float* __restrict__ dd, int* __restrict__ counts){
    int g = blockIdx.x*256 + threadIdx.x;     // 16896 threads exactly
    if (g >= IMGS*HW) return;
    int bn = g/HW, p = g - bn*HW;
    float scale = expf(lsc[0]);
    float sh    = shf[0];
    float sig   = fminf(fmaxf(expf(lsg[0]), 0.1f), 20.f);
    float inv   = 1.f/sig;
    float metric = fminf(fmaxf(scale*rel[g] + sh, 0.5f), 150.f);
    float nb = fminf(fmaxf(rintf(metric), 1.f), 59.f);
    float mx = -fabsf(metric - nb)*inv;
    float sum = 0.f;
    for (int d = 0; d < DD; ++d)
        sum += expf(-fabsf(metric - (float)(d+1))*inv - mx);
    float rs = 1.f/sum;
    for (int d = 0; d < DD; ++d){
        int idx = (bn*DD + d)*HW + p;
        dd[idx] = expf(-fabsf(metric - (float)(d+1))*inv - mx)*rs;
        atomicAdd(&counts[vids[idx]], 1);
    }
}

__global__ void scan_kernel(const int* __restrict__ counts, int* __restrict__ offsets){
    __shared__ int part[256];
    int t = threadIdx.x;
    int base = t*64;
    int s = 0;
    for (int i = 0; i < 64; ++i) s += counts[base+i];
    part[t] = s;
    __syncthreads();
    for (int off = 1; off < 256; off <<= 1){
        int v = (t >= off) ? part[t-off] : 0;
        __syncthreads();
        part[t] += v;
        __syncthreads();
    }
    int run = (t == 0) ? 0 : part[t-1];
    for (int i = 0; i < 64; ++i){
        offsets[base+i] = run;
        run += counts[base+i];
    }
}

__global__ void fill_kernel(const float* __restrict__ dd, const int* __restrict__ vids,
                            const int* __restrict__ offsets, int* __restrict__ cursor,
                            int2* __restrict__ records){
    int g = blockIdx.x*256 + threadIdx.x;
    if (g >= IMGS*HW) return;
    int bn = g/HW, p = g - bn*HW;
    for (int d = 0; d < DD; ++d){
        int idx = (bn*DD + d)*HW + p;
        int v   = vids[idx];
        float w = dd[idx];
        int pos = atomicAdd(&cursor[v], 1);
        records[offsets[v] + pos] = make_int2(g, __float_as_int(w));
    }
}

// ---------------- MFMA conv (implicit GEMM, fp16 hi/lo 3-term split) -------
// tile 128 pix x 128 co, BK=64, 256 threads = 4 waves (2x2), wave tile 64x64.
// A source: pixel-major [img*2816+pix][256] fp16 (hi/lo planes)
// B source: [tap][co][ci] fp16 (hi/lo planes)
// LDS planes (16KB each): Ah Al Bh Bl, rows of 64 halfs, XOR-swizzled:
//   physical 16B-slot of (row m, k-octet c) = m*8 + (c ^ (m&7))
template<int TAPS, bool BN_RELU, bool F32OUT, int COT>
__global__ __launch_bounds__(256,1) void conv_mfma(
    const _Float16* __restrict__ inH, const _Float16* __restrict__ inL,
    const _Float16* __restrict__ wHp, const _Float16* __restrict__ wLp,
    const float* __restrict__ scale, const float* __restrict__ bias,
    float* __restrict__ outF,
    _Float16* __restrict__ outH, _Float16* __restrict__ outL,
    const _Float16* __restrict__ zpad)
{
    __shared__ __align__(16) _Float16 lds[4*8192];

    const int t    = threadIdx.x;
    const int wave = t >> 6;
    const int lane = t & 63;
    const int g    = lane >> 4;
    const int l15  = lane & 15;
    const int wr   = wave >> 1, wc = wave & 1;
    const int img  = blockIdx.z;
    const int m0   = blockIdx.x*128;        // pixel base within image
    const int n0   = blockIdx.y*128;        // out-channel base
    const int imgbase = img*HW;

    // staging slot constants (4 slots of 16B per plane per thread)
    int mrow[4], koct[4], py[4], px[4], boff[4];
#pragma unroll
    for (int i = 0; i < 4; ++i){
        int p = wave*256 + i*64 + lane;       // slot in [0,1024)
        mrow[i] = p >> 3;
        koct[i] = ((p & 7) ^ (mrow[i] & 7))*8;    // element offset in [0,64)
        int pp = m0 + mrow[i];
        py[i] = pp/88; px[i] = pp - py[i]*88;
        boff[i] = (n0 + mrow[i])*256 + koct[i];
    }
    // fragment row constants
    int arow[4], brow[4];
#pragma unroll
    for (int f = 0; f < 4; ++f){
        arow[f] = wr*64 + f*16 + l15;
        brow[f] = wc*64 + f*16 + l15;
    }

    f32x4 acc[4][4];
#pragma unroll
    for (int i = 0; i < 4; ++i)
#pragma unroll
        for (int j = 0; j < 4; ++j) acc[i][j] = (f32x4){0.f,0.f,0.f,0.f};

    for (int tap = 0; tap < TAPS; ++tap){
        const int dy = (TAPS == 9) ? (tap/3 - 1) : 0;
        const int dx = (TAPS == 9) ? (tap%3 - 1) : 0;
        int aoff[4]; bool av[4];
#pragma unroll
        for (int i = 0; i < 4; ++i){
            int yy = py[i] + dy, xx = px[i] + dx;
            av[i]   = ((unsigned)yy < 32u) && ((unsigned)xx < 88u);
            aoff[i] = (imgbase + yy*88 + xx)*256 + koct[i];
        }
        const _Float16* wbH = wHp + (size_t)tap*COT*256;
        const _Float16* wbL = wLp + (size_t)tap*COT*256;

        for (int ci0 = 0; ci0 < 256; ci0 += 64){
            __syncthreads();   // prior compute done reading LDS
#pragma unroll
            for (int i = 0; i < 4; ++i){
                const int lo = (wave*4 + i)*512;
                const _Float16* gah = av[i] ? (inH + aoff[i] + ci0) : zpad;
                const _Float16* gal = av[i] ? (inL + aoff[i] + ci0) : zpad;
                glds16(gah,               lds + 0*8192 + lo);
                glds16(gal,               lds + 1*8192 + lo);
                glds16(wbH + boff[i]+ci0, lds + 2*8192 + lo);
                glds16(wbL + boff[i]+ci0, lds + 3*8192 + lo);
            }
            __syncthreads();   // staging complete (vmcnt drained by barrier)

#pragma unroll
            for (int ks = 0; ks < 2; ++ks){
                half8 ah[4], al[4], bh[4], bl[4];
#pragma unroll
                for (int f = 0; f < 4; ++f){
                    int ea = arow[f]*64 + (((ks*4 + g) ^ (arow[f] & 7))*8);
                    int eb = brow[f]*64 + (((ks*4 + g) ^ (brow[f] & 7))*8);
                    ah[f] = *(const half8*)(lds + 0*8192 + ea);
                    al[f] = *(const half8*)(lds + 1*8192 + ea);
                    bh[f] = *(const half8*)(lds + 2*8192 + eb);
                    bl[f] = *(const half8*)(lds + 3*8192 + eb);
                }
#pragma unroll
                for (int mi = 0; mi < 4; ++mi)
#pragma unroll
                for (int ni = 0; ni < 4; ++ni){
                    acc[mi][ni] = __builtin_amdgcn_mfma_f32_16x16x32_f16(ah[mi], bh[ni], acc[mi][ni], 0,0,0);
                    acc[mi][ni] = __builtin_amdgcn_mfma_f32_16x16x32_f16(ah[mi], bl[ni], acc[mi][ni], 0,0,0);
                    acc[mi][ni] = __builtin_amdgcn_mfma_f32_16x16x32_f16(al[mi], bh[ni], acc[mi][ni], 0,0,0);
                }
            }
        }
    }

    // epilogue: C/D layout col = lane&15 (co), row = (lane>>4)*4 + r (pixel)
#pragma unroll
    for (int ni = 0; ni < 4; ++ni){
        int co = n0 + wc*64 + ni*16 + l15;
        float sc = BN_RELU ? scale[co] : 0.f;
        float bi = bias[co];
#pragma unroll
        for (int mi = 0; mi < 4; ++mi){
            f32x4 v = acc[mi][ni];
            int rb = imgbase + m0 + wr*64 + mi*16 + g*4;
#pragma unroll
            for (int r = 0; r < 4; ++r){
                float y;
                if (BN_RELU) y = fmaxf(fmaf(v[r], sc, bi), 0.f);
                else         y = v[r] + bi;
                size_t o = (size_t)(rb + r)*COT + co;
                if constexpr (F32OUT){
                    outF[o] = y;
                } else {
                    _Float16 h = (_Float16)y;
                    outH[o] = h;
                    outL[o] = (_Float16)(y - (float)h);
                }
            }
        }
    }
}

// ---------------- atomic-free splat: gather per voxel ----------------

__global__ __launch_bounds__(128) void gather_kernel(
    const int2* __restrict__ records, const int* __restrict__ offsets,
    const int* __restrict__ counts, const float* __restrict__ feat,
    float* __restrict__ bev_t){
    int v = blockIdx.x;
    int c = threadIdx.x;
    int off = offsets[v], n = counts[v];
    float acc = 0.f;
    for (int i = 0; i < n; ++i){
        int2 r = records[off + i];
        acc = fmaf(__int_as_float(r.y), feat[(size_t)r.x*COUT + c], acc);
    }
    bev_t[(size_t)v*COUT + c] = acc;
}

// bev_t[v][c] -> out[c][v]
__global__ void transpose_out(const float* __restrict__ bev_t, float* __restrict__ out){
    __shared__ float tile[32][33];
    int v0 = blockIdx.x*32, c0 = blockIdx.y*32;
    int tx = threadIdx.x & 31, ty = threadIdx.x >> 5;
#pragma unroll
    for (int k = 0; k < 4; ++k)
        tile[ty + 8*k][tx] = bev_t[(size_t)(v0 + ty + 8*k)*COUT + c0 + tx];
    __syncthreads();
#pragma unroll
    for (int k = 0; k < 4; ++k)
        out[(size_t)(c0 + ty + 8*k)*NV + v0 + tx] = tile[tx][ty + 8*k];
}

// ---------------- launch ----------------

extern "C" void kernel_launch(void* const* d_in, const int* in_sizes, int n_in,
                              void* d_out, int out_size, void* d_ws, size_t ws_size,
                              hipStream_t stream){
    const float* rel  = (const float*)d_in[0];
    const float* imgf = (const float*)d_in[1];
    const int*   vids = (const int*)d_in[2];
    const float* lsc  = (const float*)d_in[3];
    const float* shf  = (const float*)d_in[4];
    const float* lsg  = (const float*)d_in[5];
    const float* w1   = (const float*)d_in[6];
    const float* b1   = (const float*)d_in[7];
    const float* g1   = (const float*)d_in[8];
    const float* bb1  = (const float*)d_in[9];
    const float* m1   = (const float*)d_in[10];
    const float* v1   = (const float*)d_in[11];
    const float* w2   = (const float*)d_in[12];
    const float* b2   = (const float*)d_in[13];
    const float* g2   = (const float*)d_in[14];
    const float* bb2  = (const float*)d_in[15];
    const float* m2   = (const float*)d_in[16];
    const float* v2   = (const float*)d_in[17];
    const float* w3   = (const float*)d_in[18];
    const float* b3   = (const float*)d_in[19];

    char* ws = (char*)d_ws;
    size_t o = 0;
    auto alloc = [&](size_t bytes)->char*{
        char* p = ws + o;
        o += (bytes + 255) & ~(size_t)255;
        return p;
    };
    int* counts  = (int*)alloc((size_t)(2*NV + 64)*4);   // counts | cursor | zpad
    int* cursor  = counts + NV;
    const _Float16* zpad16 = (const _Float16*)(counts + 2*NV);
    int* offsets = (int*)alloc((size_t)NV*4);

    _Float16* wT1H = (_Float16*)alloc((size_t)9*256*256*2);
    _Float16* wT1L = (_Float16*)alloc((size_t)9*256*256*2);
    _Float16* wT2H = (_Float16*)alloc((size_t)9*256*256*2);
    _Float16* wT2L = (_Float16*)alloc((size_t)9*256*256*2);
    _Float16* wT3H = (_Float16*)alloc((size_t)128*256*2);
    _Float16* wT3L = (_Float16*)alloc((size_t)128*256*2);
    float* s1 = (float*)alloc(256*4);
    float* t1 = (float*)alloc(256*4);
    float* s2 = (float*)alloc(256*4);
    float* t2 = (float*)alloc(256*4);

    _Float16* in0H = (_Float16*)alloc((size_t)IMGS*HW*256*2);   // 8.65 MB
    _Float16* in0L = (_Float16*)alloc((size_t)IMGS*HW*256*2);
    _Float16* h1H  = (_Float16*)alloc((size_t)IMGS*HW*256*2);
    _Float16* h1L  = (_Float16*)alloc((size_t)IMGS*HW*256*2);
    float* feat_t  = (float*)alloc((size_t)IMGS*HW*COUT*4);     // 8.65 MB
    float* bev_t   = (float*)alloc((size_t)NV*COUT*4);          // 8 MB
    // aliases: h2 planes reuse in0 (dead after conv1); splat scratch reuses h1
    _Float16* h2H = in0H;
    _Float16* h2L = in0L;
    float* dd      = (float*)h1H;   // 4 MB  <= 8.65 MB
    int2*  records = (int2*)h1L;    // 8 MB  <= 8.65 MB

    bn_prep<<<1,256,0,stream>>>(b1,g1,bb1,m1,v1, b2,g2,bb2,m2,v2, s1,t1,s2,t2);
    zero_kernel<<<(2*NV + 64 + 255)/256,256,0,stream>>>(counts, 2*NV + 64);
    wsplit<<<2304,256,0,stream>>>(w1, wT1H, wT1L, 256, 256, 9);
    wsplit<<<2304,256,0,stream>>>(w2, wT2H, wT2L, 256, 256, 9);
    wsplit<<<128,256,0,stream>>>(w3, wT3H, wT3L, 128, 256, 1);
    tsplit<<<dim3(88,8,6),256,0,stream>>>(imgf, in0H, in0L);

    conv_mfma<9,true ,false,256><<<dim3(22,2,6),256,0,stream>>>(
        in0H, in0L, wT1H, wT1L, s1, t1, nullptr, h1H, h1L, zpad16);
    conv_mfma<9,true ,false,256><<<dim3(22,2,6),256,0,stream>>>(
        h1H, h1L, wT2H, wT2L, s2, t2, nullptr, h2H, h2L, zpad16);
    conv_mfma<1,false,true ,128><<<dim3(22,1,6),256,0,stream>>>(
        h2H, h2L, wT3H, wT3L, s1, b3, feat_t, nullptr, nullptr, zpad16);

    depth_count<<<66,256,0,stream>>>(rel, vids, lsc, shf, lsg, dd, counts);
    scan_kernel<<<1,256,0,stream>>>(counts, offsets);
    fill_kernel<<<66,256,0,stream>>>(dd, vids, offsets, cursor, records);

    gather_kernel<<<NV,128,0,stream>>>(records, offsets, counts, feat_t, bev_t);
    transpose_out<<<dim3(512,4),256,0,stream>>>(bev_t, (float*)d_out);
}

// Round 3
// 431.559 us; speedup vs baseline: 2.5726x; 1.1874x over previous
//
#include <hip/hip_runtime.h>
#include <math.h>

#define HW   2816           // 32*88
#define IMGS 6
#define DD   59
#define NV   16384          // 128*128 BEV cells (B=1)
#define COUT 128

typedef _Float16 half8 __attribute__((ext_vector_type(8)));
typedef _Float16 half2v __attribute__((ext_vector_type(2)));
typedef float f32x4 __attribute__((ext_vector_type(4)));

__device__ __forceinline__ void glds16(const void* g, const _Float16* l){
    __builtin_amdgcn_global_load_lds(
        (const __attribute__((address_space(1))) void*)g,
        (__attribute__((address_space(3))) void*)(_Float16*)l, 16, 0, 0);
}

// ---------------- small prep kernels ----------------

__global__ void zero_kernel(int* __restrict__ p, int n){
    int i = blockIdx.x*256 + threadIdx.x;
    if (i < n) p[i] = 0;
}

__global__ void bn_prep(const float* __restrict__ c1b, const float* __restrict__ g1,
                        const float* __restrict__ bb1, const float* __restrict__ m1,
                        const float* __restrict__ v1,
                        const float* __restrict__ c2b, const float* __restrict__ g2,
                        const float* __restrict__ bb2, const float* __restrict__ m2,
                        const float* __restrict__ v2,
                        float* __restrict__ s1, float* __restrict__ t1,
                        float* __restrict__ s2, float* __restrict__ t2){
    int c = threadIdx.x;   // 256
    float i1 = g1[c]/sqrtf(v1[c]+1e-3f);
    s1[c] = i1; t1[c] = (c1b[c]-m1[c])*i1 + bb1[c];
    float i2 = g2[c]/sqrtf(v2[c]+1e-3f);
    s2[c] = i2; t2[c] = (c2b[c]-m2[c])*i2 + bb2[c];
}

// OIHW -> [tap][co][ci] fp16 hi/lo split
__global__ void wsplit(const float* __restrict__ w, _Float16* __restrict__ wh,
                       _Float16* __restrict__ wl, int CO, int CI, int KK){
    int idx = blockIdx.x*256 + threadIdx.x;
    if (idx >= CO*CI*KK) return;
    int co  = idx/(CI*KK);
    int r   = idx - co*CI*KK;
    int ci  = r/KK;
    int tap = r - ci*KK;
    float v = w[idx];
    _Float16 h = (_Float16)v;
    size_t o = ((size_t)tap*CO + co)*CI + ci;
    wh[o] = h; wl[o] = (_Float16)(v - (float)h);
}

// imgf [img][ci=256][pix=2816] fp32 -> pixel-major fp16 hi/lo [img*2816+pix][256]
__global__ void tsplit(const float* __restrict__ imgf,
                       _Float16* __restrict__ inH, _Float16* __restrict__ inL){
    __shared__ float tile[32][33];
    int img = blockIdx.z;
    int p0 = blockIdx.x*32, c0 = blockIdx.y*32;
    int tx = threadIdx.x & 31, ty = threadIdx.x >> 5;   // 32 x 8
#pragma unroll
    for (int k = 0; k < 4; ++k)
        tile[ty + 8*k][tx] = imgf[((size_t)(img*256 + c0 + ty + 8*k))*HW + p0 + tx];
    __syncthreads();
#pragma unroll
    for (int k = 0; k < 4; ++k){
        int pr = ty + 8*k, cc = tx;
        float v = tile[cc][pr];
        _Float16 h = (_Float16)v;
        size_t o = ((size_t)(img*HW + p0 + pr))*256 + c0 + cc;
        inH[o] = h; inL[o] = (_Float16)(v - (float)h);
    }
}

// ---------------- depth distribution + voxel histogram ----------------

__global__ void depth_count(const float* __restrict__ rel, const int* __restrict__ vids,
                            const float* __restrict__ lsc, const float* __restrict__ shf,
                            const float* __restrict__ lsg,
                            float* __restrict__ dd, int* __restrict__ counts){
    int g = blockIdx.x*256 + threadIdx.x;     // 16896 threads exactly
    if (g >= IMGS*HW) return;
    int bn = g/HW, p = g - bn*HW;
    float scale = expf(lsc[0]);
    float sh    = shf[0];
    float sig   = fminf(fmaxf(expf(lsg[0]), 0.1f), 20.f);
    float inv   = 1.f/sig;
    float metric = fminf(fmaxf(scale*rel[g] + sh, 0.5f), 150.f);
    float nb = fminf(fmaxf(rintf(metric), 1.f), 59.f);
    float mx = -fabsf(metric - nb)*inv;
    float sum = 0.f;
    for (int d = 0; d < DD; ++d)
        sum += expf(-fabsf(metric - (float)(d+1))*inv - mx);
    float rs = 1.f/sum;
    for (int d = 0; d < DD; ++d){
        int idx = (bn*DD + d)*HW + p;
        dd[idx] = expf(-fabsf(metric - (float)(d+1))*inv - mx)*rs;
        atomicAdd(&counts[vids[idx]], 1);
    }
}

__global__ void scan_kernel(const int* __restrict__ counts, int* __restrict__ offsets){
    __shared__ int part[256];
    int t = threadIdx.x;
    int base = t*64;
    int s = 0;
    for (int i = 0; i < 64; ++i) s += counts[base+i];
    part[t] = s;
    __syncthreads();
    for (int off = 1; off < 256; off <<= 1){
        int v = (t >= off) ? part[t-off] : 0;
        __syncthreads();
        part[t] += v;
        __syncthreads();
    }
    int run = (t == 0) ? 0 : part[t-1];
    for (int i = 0; i < 64; ++i){
        offsets[base+i] = run;
        run += counts[base+i];
    }
}

__global__ void fill_kernel(const float* __restrict__ dd, const int* __restrict__ vids,
                            const int* __restrict__ offsets, int* __restrict__ cursor,
                            int2* __restrict__ records){
    int g = blockIdx.x*256 + threadIdx.x;
    if (g >= IMGS*HW) return;
    int bn = g/HW, p = g - bn*HW;
    for (int d = 0; d < DD; ++d){
        int idx = (bn*DD + d)*HW + p;
        int v   = vids[idx];
        float w = dd[idx];
        int pos = atomicAdd(&cursor[v], 1);
        records[offsets[v] + pos] = make_int2(g, __float_as_int(w));
    }
}

// ---------------- MFMA conv (implicit GEMM, fp16 hi/lo 3-term split) -------
// tile 64 pix x 128 co, BK=64, 256 threads = 4 waves (2x2), wave tile 32x64.
// LDS 48KB -> 3 blocks/CU.  A: [64px][64k] planes 8KB; B: [128co][64k] 16KB.
// 16B-slot swizzle: slot(row m, k-octet c) = m*8 + (c ^ (m&7))
template<int TAPS, bool BN_RELU, bool F16OUT, int COT>
__global__ __launch_bounds__(256,3) void conv_mfma(
    const _Float16* __restrict__ inH, const _Float16* __restrict__ inL,
    const _Float16* __restrict__ wHp, const _Float16* __restrict__ wLp,
    const float* __restrict__ scale, const float* __restrict__ bias,
    _Float16* __restrict__ outH, _Float16* __restrict__ outL,
    const _Float16* __restrict__ zpad)
{
    __shared__ __align__(16) _Float16 lds[24576];   // Ah 0 | Al 4096 | Bh 8192 | Bl 16384

    const int t    = threadIdx.x;
    const int wave = t >> 6;
    const int lane = t & 63;
    const int g    = lane >> 4;
    const int l15  = lane & 15;
    const int wr   = wave >> 1, wc = wave & 1;
    const int g0   = blockIdx.x*64;          // global pixel base (tiles don't cross images: 2816%64==0)
    const int img  = g0/HW;
    const int pbase = g0 - img*HW;
    const int n0   = blockIdx.y*128;
    const int imgbase = img*HW;

    // A staging: 512 slots of 16B, 2 per thread
    int aK[2], aPy[2], aPx[2], aLo[2];
#pragma unroll
    for (int i = 0; i < 2; ++i){
        int s = wave*128 + i*64 + lane;
        int row = s >> 3;
        aK[i] = ((s & 7) ^ (row & 7))*8;
        int pp = pbase + row;
        aPy[i] = pp/88; aPx[i] = pp - aPy[i]*88;
        aLo[i] = (wave*128 + i*64)*8;
    }
    // B staging: 1024 slots, 4 per thread
    int bOff[4], bLo[4];
#pragma unroll
    for (int i = 0; i < 4; ++i){
        int s = wave*256 + i*64 + lane;
        int row = s >> 3;
        bOff[i] = (n0 + row)*256 + ((s & 7) ^ (row & 7))*8;
        bLo[i] = (wave*256 + i*64)*8;
    }
    int arow[2], brow[4];
#pragma unroll
    for (int f = 0; f < 2; ++f) arow[f] = wr*32 + f*16 + l15;
#pragma unroll
    for (int f = 0; f < 4; ++f) brow[f] = wc*64 + f*16 + l15;

    f32x4 acc[2][4];
#pragma unroll
    for (int i = 0; i < 2; ++i)
#pragma unroll
        for (int j = 0; j < 4; ++j) acc[i][j] = (f32x4){0.f,0.f,0.f,0.f};

    for (int tap = 0; tap < TAPS; ++tap){
        const int dy = (TAPS == 9) ? (tap/3 - 1) : 0;
        const int dx = (TAPS == 9) ? (tap%3 - 1) : 0;
        int aoff[2]; bool av[2];
#pragma unroll
        for (int i = 0; i < 2; ++i){
            int yy = aPy[i] + dy, xx = aPx[i] + dx;
            av[i]   = ((unsigned)yy < 32u) && ((unsigned)xx < 88u);
            aoff[i] = (imgbase + yy*88 + xx)*256 + aK[i];
        }
        const _Float16* wbH = wHp + (size_t)tap*COT*256;
        const _Float16* wbL = wLp + (size_t)tap*COT*256;

        for (int ci0 = 0; ci0 < 256; ci0 += 64){
            __syncthreads();
#pragma unroll
            for (int i = 0; i < 2; ++i){
                const _Float16* gah = av[i] ? (inH + aoff[i] + ci0) : zpad;
                const _Float16* gal = av[i] ? (inL + aoff[i] + ci0) : zpad;
                glds16(gah, lds + 0    + aLo[i]);
                glds16(gal, lds + 4096 + aLo[i]);
            }
#pragma unroll
            for (int i = 0; i < 4; ++i){
                glds16(wbH + bOff[i] + ci0, lds + 8192  + bLo[i]);
                glds16(wbL + bOff[i] + ci0, lds + 16384 + bLo[i]);
            }
            __syncthreads();

#pragma unroll
            for (int ks = 0; ks < 2; ++ks){
                half8 ah[2], al[2], bh[4], bl[4];
#pragma unroll
                for (int f = 0; f < 2; ++f){
                    int ea = arow[f]*64 + (((ks*4 + g) ^ (arow[f] & 7))*8);
                    ah[f] = *(const half8*)(lds + 0    + ea);
                    al[f] = *(const half8*)(lds + 4096 + ea);
                }
#pragma unroll
                for (int f = 0; f < 4; ++f){
                    int eb = brow[f]*64 + (((ks*4 + g) ^ (brow[f] & 7))*8);
                    bh[f] = *(const half8*)(lds + 8192  + eb);
                    bl[f] = *(const half8*)(lds + 16384 + eb);
                }
#pragma unroll
                for (int mi = 0; mi < 2; ++mi)
#pragma unroll
                for (int ni = 0; ni < 4; ++ni){
                    acc[mi][ni] = __builtin_amdgcn_mfma_f32_16x16x32_f16(ah[mi], bh[ni], acc[mi][ni], 0,0,0);
                    acc[mi][ni] = __builtin_amdgcn_mfma_f32_16x16x32_f16(ah[mi], bl[ni], acc[mi][ni], 0,0,0);
                    acc[mi][ni] = __builtin_amdgcn_mfma_f32_16x16x32_f16(al[mi], bh[ni], acc[mi][ni], 0,0,0);
                }
            }
        }
    }

    // epilogue: C/D col = lane&15 (co), row = (lane>>4)*4 + r (pixel)
#pragma unroll
    for (int ni = 0; ni < 4; ++ni){
        int co = n0 + wc*64 + ni*16 + l15;
        float sc = BN_RELU ? scale[co] : 0.f;
        float bi = bias[co];
#pragma unroll
        for (int mi = 0; mi < 2; ++mi){
            f32x4 v = acc[mi][ni];
            int rb = g0 + wr*32 + mi*16 + g*4;
#pragma unroll
            for (int r = 0; r < 4; ++r){
                float y;
                if (BN_RELU) y = fmaxf(fmaf(v[r], sc, bi), 0.f);
                else         y = v[r] + bi;
                size_t o = (size_t)(rb + r)*COT + co;
                if constexpr (F16OUT){
                    outH[o] = (_Float16)y;
                } else {
                    _Float16 h = (_Float16)y;
                    outH[o] = h;
                    outL[o] = (_Float16)(y - (float)h);
                }
            }
        }
    }
}

// ---------------- atomic-free splat: gather per voxel (fp16 feat) ----------
// one wave per voxel, lane holds 2 channels; records loop unrolled x4
__global__ __launch_bounds__(256,8) void gather_kernel(
    const int2* __restrict__ records, const int* __restrict__ offsets,
    const int* __restrict__ counts, const _Float16* __restrict__ feat16,
    float* __restrict__ bev_t){
    int v    = blockIdx.x*4 + (threadIdx.x >> 6);
    int lane = threadIdx.x & 63;
    int off = offsets[v], n = counts[v];
    float a0 = 0.f, a1 = 0.f;
    int i = 0;
    for (; i + 4 <= n; i += 4){
        int2 r0 = records[off+i+0];
        int2 r1 = records[off+i+1];
        int2 r2 = records[off+i+2];
        int2 r3 = records[off+i+3];
        half2v f0 = *(const half2v*)(feat16 + (size_t)r0.x*COUT + lane*2);
        half2v f1 = *(const half2v*)(feat16 + (size_t)r1.x*COUT + lane*2);
        half2v f2 = *(const half2v*)(feat16 + (size_t)r2.x*COUT + lane*2);
        half2v f3 = *(const half2v*)(feat16 + (size_t)r3.x*COUT + lane*2);
        float w0 = __int_as_float(r0.y), w1 = __int_as_float(r1.y);
        float w2 = __int_as_float(r2.y), w3 = __int_as_float(r3.y);
        a0 = fmaf(w0, (float)f0[0], a0); a1 = fmaf(w0, (float)f0[1], a1);
        a0 = fmaf(w1, (float)f1[0], a0); a1 = fmaf(w1, (float)f1[1], a1);
        a0 = fmaf(w2, (float)f2[0], a0); a1 = fmaf(w2, (float)f2[1], a1);
        a0 = fmaf(w3, (float)f3[0], a0); a1 = fmaf(w3, (float)f3[1], a1);
    }
    for (; i < n; ++i){
        int2 r = records[off+i];
        half2v f = *(const half2v*)(feat16 + (size_t)r.x*COUT + lane*2);
        float w = __int_as_float(r.y);
        a0 = fmaf(w, (float)f[0], a0); a1 = fmaf(w, (float)f[1], a1);
    }
    *(float2*)(bev_t + (size_t)v*COUT + lane*2) = make_float2(a0, a1);
}

// bev_t[v][c] -> out[c][v]
__global__ void transpose_out(const float* __restrict__ bev_t, float* __restrict__ out){
    __shared__ float tile[32][33];
    int v0 = blockIdx.x*32, c0 = blockIdx.y*32;
    int tx = threadIdx.x & 31, ty = threadIdx.x >> 5;
#pragma unroll
    for (int k = 0; k < 4; ++k)
        tile[ty + 8*k][tx] = bev_t[(size_t)(v0 + ty + 8*k)*COUT + c0 + tx];
    __syncthreads();
#pragma unroll
    for (int k = 0; k < 4; ++k)
        out[(size_t)(c0 + ty + 8*k)*NV + v0 + tx] = tile[tx][ty + 8*k];
}

// ---------------- launch ----------------

extern "C" void kernel_launch(void* const* d_in, const int* in_sizes, int n_in,
                              void* d_out, int out_size, void* d_ws, size_t ws_size,
                              hipStream_t stream){
    const float* rel  = (const float*)d_in[0];
    const float* imgf = (const float*)d_in[1];
    const int*   vids = (const int*)d_in[2];
    const float* lsc  = (const float*)d_in[3];
    const float* shf  = (const float*)d_in[4];
    const float* lsg  = (const float*)d_in[5];
    const float* w1   = (const float*)d_in[6];
    const float* b1   = (const float*)d_in[7];
    const float* g1   = (const float*)d_in[8];
    const float* bb1  = (const float*)d_in[9];
    const float* m1   = (const float*)d_in[10];
    const float* v1   = (const float*)d_in[11];
    const float* w2   = (const float*)d_in[12];
    const float* b2   = (const float*)d_in[13];
    const float* g2   = (const float*)d_in[14];
    const float* bb2  = (const float*)d_in[15];
    const float* m2   = (const float*)d_in[16];
    const float* v2   = (const float*)d_in[17];
    const float* w3   = (const float*)d_in[18];
    const float* b3   = (const float*)d_in[19];

    char* ws = (char*)d_ws;
    size_t o = 0;
    auto alloc = [&](size_t bytes)->char*{
        char* p = ws + o;
        o += (bytes + 255) & ~(size_t)255;
        return p;
    };
    int* counts  = (int*)alloc((size_t)(2*NV + 64)*4);   // counts | cursor | zpad
    int* cursor  = counts + NV;
    const _Float16* zpad16 = (const _Float16*)(counts + 2*NV);
    int* offsets = (int*)alloc((size_t)NV*4);

    _Float16* wT1H = (_Float16*)alloc((size_t)9*256*256*2);
    _Float16* wT1L = (_Float16*)alloc((size_t)9*256*256*2);
    _Float16* wT2H = (_Float16*)alloc((size_t)9*256*256*2);
    _Float16* wT2L = (_Float16*)alloc((size_t)9*256*256*2);
    _Float16* wT3H = (_Float16*)alloc((size_t)128*256*2);
    _Float16* wT3L = (_Float16*)alloc((size_t)128*256*2);
    float* s1 = (float*)alloc(256*4);
    float* t1 = (float*)alloc(256*4);
    float* s2 = (float*)alloc(256*4);
    float* t2 = (float*)alloc(256*4);

    _Float16* in0H = (_Float16*)alloc((size_t)IMGS*HW*256*2);   // 8.65 MB
    _Float16* in0L = (_Float16*)alloc((size_t)IMGS*HW*256*2);
    _Float16* h1H  = (_Float16*)alloc((size_t)IMGS*HW*256*2);
    _Float16* h1L  = (_Float16*)alloc((size_t)IMGS*HW*256*2);
    _Float16* feat16 = (_Float16*)alloc((size_t)IMGS*HW*COUT*2);  // 4.3 MB
    float* bev_t   = (float*)alloc((size_t)NV*COUT*4);            // 8 MB
    // aliases: h2 planes reuse in0 (dead after conv1); splat scratch reuses h1
    _Float16* h2H = in0H;
    _Float16* h2L = in0L;
    float* dd      = (float*)h1H;   // 4 MB  <= 8.65 MB
    int2*  records = (int2*)h1L;    // 8 MB  <= 8.65 MB

    bn_prep<<<1,256,0,stream>>>(b1,g1,bb1,m1,v1, b2,g2,bb2,m2,v2, s1,t1,s2,t2);
    zero_kernel<<<(2*NV + 64 + 255)/256,256,0,stream>>>(counts, 2*NV + 64);
    wsplit<<<2304,256,0,stream>>>(w1, wT1H, wT1L, 256, 256, 9);
    wsplit<<<2304,256,0,stream>>>(w2, wT2H, wT2L, 256, 256, 9);
    wsplit<<<128,256,0,stream>>>(w3, wT3H, wT3L, 128, 256, 1);
    tsplit<<<dim3(88,8,6),256,0,stream>>>(imgf, in0H, in0L);

    conv_mfma<9,true ,false,256><<<dim3(264,2),256,0,stream>>>(
        in0H, in0L, wT1H, wT1L, s1, t1, h1H, h1L, zpad16);
    conv_mfma<9,true ,false,256><<<dim3(264,2),256,0,stream>>>(
        h1H, h1L, wT2H, wT2L, s2, t2, h2H, h2L, zpad16);
    conv_mfma<1,false,true ,128><<<dim3(264,1),256,0,stream>>>(
        h2H, h2L, wT3H, wT3L, s1, b3, feat16, nullptr, zpad16);

    depth_count<<<66,256,0,stream>>>(rel, vids, lsc, shf, lsg, dd, counts);
    scan_kernel<<<1,256,0,stream>>>(counts, offsets);
    fill_kernel<<<66,256,0,stream>>>(dd, vids, offsets, cursor, records);

    gather_kernel<<<4096,256,0,stream>>>(records, offsets, counts, feat16, bev_t);
    transpose_out<<<dim3(512,4),256,0,stream>>>(bev_t, (float*)d_out);
}